// Round 7
// baseline (371.024 us; speedup 1.0000x reference)
//
#include <hip/hip_runtime.h>
#include <hip/hip_bf16.h>

#define TT 32768   // B*S tokens
#define S_LEN 1024
#define B_SZ 32
#define H_N 2

// f32 intermediates as device globals: graph-capture safe, fully overwritten
// before being read each call -> deterministic.
__device__ __align__(16) float g_Q[TT * 8];
__device__ __align__(16) float g_K[TT * 8];
__device__ __align__(16) float g_V[TT * 8];
__device__ __align__(16) float g_C[TT * 8];

// ---------------------------------------------------------------------------
// 8-qubit statevector, one token per 64-lane wave.
// Flat index b = lane*4 + j: qubit q in {0..5} <-> lane bit (5-q);
// qubit6 <-> j bit1; qubit7 <-> j bit0. (qubit 0 = MSB of flat index.)
// Equivalence to the literal scalar transcription is established by
// bit-identical outputs across rounds 1-3.
// ---------------------------------------------------------------------------

__device__ __forceinline__ void embed_state(const float* __restrict__ xt, int lane,
                                            float pre[4], float pim[4])
{
    float ch[8], sh[8];
#pragma unroll
    for (int q = 0; q < 8; ++q) {
        float hh = 0.5f * xt[q];
        __sincosf(hh, &sh[q], &ch[q]);
    }
    float ml = 1.f;
#pragma unroll
    for (int q = 0; q < 6; ++q) ml *= ((lane >> (5 - q)) & 1) ? sh[q] : ch[q];
    int kl = __popc(lane & 63);
    float aa[4] = {ml * ch[6] * ch[7], ml * ch[6] * sh[7],
                   ml * sh[6] * ch[7], ml * sh[6] * sh[7]};
    const int kadd[4] = {0, 1, 1, 2};
#pragma unroll
    for (int j = 0; j < 4; ++j) {
        int k = (kl + kadd[j]) & 3;           // amp = a * (-i)^k
        float a = aa[j];
        pre[j] = (k == 0) ? a : ((k == 2) ? -a : 0.f);
        pim[j] = (k == 1) ? -a : ((k == 3) ? a : 0.f);
    }
}

__device__ __forceinline__ void circuit(float re[4], float im[4], int lane,
                                        const float* __restrict__ w, float ev[8])
{
#pragma unroll
    for (int l = 0; l < 2; ++l) {
        // RX on qubits 0..5 (cross-lane)
#pragma unroll
        for (int q = 0; q < 6; ++q) {
            float c, s;
            __sincosf(0.5f * w[l * 8 + q], &s, &c);
            int mask = 1 << (5 - q);
#pragma unroll
            for (int j = 0; j < 4; ++j) {
                float pr = __shfl_xor(re[j], mask);
                float pi = __shfl_xor(im[j], mask);
                re[j] = c * re[j] + s * pi;
                im[j] = c * im[j] - s * pr;
            }
        }
        // RX qubit 6 (slot pairs (0,2),(1,3))
        {
            float c, s;
            __sincosf(0.5f * w[l * 8 + 6], &s, &c);
            float nr0 = c * re[0] + s * im[2], ni0 = c * im[0] - s * re[2];
            float nr1 = c * re[1] + s * im[3], ni1 = c * im[1] - s * re[3];
            float nr2 = c * re[2] + s * im[0], ni2 = c * im[2] - s * re[0];
            float nr3 = c * re[3] + s * im[1], ni3 = c * im[3] - s * re[1];
            re[0] = nr0; re[1] = nr1; re[2] = nr2; re[3] = nr3;
            im[0] = ni0; im[1] = ni1; im[2] = ni2; im[3] = ni3;
        }
        // RX qubit 7 (slot pairs (0,1),(2,3))
        {
            float c, s;
            __sincosf(0.5f * w[l * 8 + 7], &s, &c);
            float nr0 = c * re[0] + s * im[1], ni0 = c * im[0] - s * re[1];
            float nr1 = c * re[1] + s * im[0], ni1 = c * im[1] - s * re[0];
            float nr2 = c * re[2] + s * im[3], ni2 = c * im[2] - s * re[3];
            float nr3 = c * re[3] + s * im[2], ni3 = c * im[3] - s * re[2];
            re[0] = nr0; re[1] = nr1; re[2] = nr2; re[3] = nr3;
            im[0] = ni0; im[1] = ni1; im[2] = ni2; im[3] = ni3;
        }
        // CNOT ring. q=0..4: ctrl = lane bit (5-q), tgt = lane bit (4-q)
#pragma unroll
        for (int q = 0; q < 5; ++q) {
            int tmask = 1 << (4 - q);
            bool cb = (lane >> (5 - q)) & 1;
#pragma unroll
            for (int j = 0; j < 4; ++j) {
                float pr = __shfl_xor(re[j], tmask);
                float pi = __shfl_xor(im[j], tmask);
                re[j] = cb ? pr : re[j];
                im[j] = cb ? pi : im[j];
            }
        }
        // q=5: ctrl = lane bit0, tgt = qubit6 (j bit1): swap (0,2),(1,3) if cb
        {
            bool cb = lane & 1;
            float r0 = re[0], r1 = re[1], r2 = re[2], r3 = re[3];
            float i0 = im[0], i1 = im[1], i2 = im[2], i3 = im[3];
            re[0] = cb ? r2 : r0; re[2] = cb ? r0 : r2;
            re[1] = cb ? r3 : r1; re[3] = cb ? r1 : r3;
            im[0] = cb ? i2 : i0; im[2] = cb ? i0 : i2;
            im[1] = cb ? i3 : i1; im[3] = cb ? i1 : i3;
        }
        // q=6: ctrl = j bit1, tgt = j bit0: swap slots 2<->3
        {
            float tr = re[2]; re[2] = re[3]; re[3] = tr;
            float ti = im[2]; im[2] = im[3]; im[3] = ti;
        }
        // q=7: ctrl = j bit0, tgt = qubit0 (lane bit5): slots 1,3 swap across lane^32
        {
            float pr1 = __shfl_xor(re[1], 32);
            float pi1 = __shfl_xor(im[1], 32);
            float pr3 = __shfl_xor(re[3], 32);
            float pi3 = __shfl_xor(im[3], 32);
            re[1] = pr1; im[1] = pi1;
            re[3] = pr3; im[3] = pi3;
        }
    }
    // <Z_q>
    float p0 = re[0] * re[0] + im[0] * im[0];
    float p1 = re[1] * re[1] + im[1] * im[1];
    float p2 = re[2] * re[2] + im[2] * im[2];
    float p3 = re[3] * re[3] + im[3] * im[3];
    float pt = p0 + p1 + p2 + p3;
    ev[6] = p0 + p1 - p2 - p3;
    ev[7] = p0 - p1 + p2 - p3;
#pragma unroll
    for (int q = 0; q < 6; ++q)
        ev[q] = ((lane >> (5 - q)) & 1) ? -pt : pt;
#pragma unroll
    for (int m = 1; m < 64; m <<= 1) {
#pragma unroll
        for (int i = 0; i < 8; ++i) ev[i] += __shfl_xor(ev[i], m);
    }
}

__global__ __launch_bounds__(256) void qkv_kernel(
    const float* __restrict__ x, const float* __restrict__ wq,
    const float* __restrict__ wk, const float* __restrict__ wv)
{
    int wid = (blockIdx.x * 256 + threadIdx.x) >> 6;   // token id
    int lane = threadIdx.x & 63;
    float pre[4], pim[4];
    embed_state(x + wid * 8, lane, pre, pim);
    const float* wptr[3] = {wq, wk, wv};
    float* optr[3] = {g_Q, g_K, g_V};
#pragma unroll
    for (int c = 0; c < 3; ++c) {
        float re[4], im[4];
#pragma unroll
        for (int j = 0; j < 4; ++j) { re[j] = pre[j]; im[j] = pim[j]; }
        float ev[8];
        circuit(re, im, lane, wptr[c], ev);
        if (lane == 0) {
#pragma unroll
            for (int i = 0; i < 8; ++i) optr[c][wid * 8 + i] = ev[i];
        }
    }
}

__global__ __launch_bounds__(256) void outc_kernel(
    const float* __restrict__ wc, float* __restrict__ out)
{
    int wid = (blockIdx.x * 256 + threadIdx.x) >> 6;
    int lane = threadIdx.x & 63;
    float pre[4], pim[4];
    embed_state(g_C + wid * 8, lane, pre, pim);
    float ev[8];
    circuit(pre, pim, lane, wc, ev);
    if (lane == 0) {
#pragma unroll
        for (int i = 0; i < 8; ++i) out[wid * 8 + i] = ev[i];   // FLOAT32 output
    }
}

// ---------------------------------------------------------------------------
// attention: grid (B*H, S/64), block 64. K,V for one (b,h) staged in LDS.
// |score| <= 2 so single-pass softmax (no max subtraction) is safe.
// ---------------------------------------------------------------------------
__global__ __launch_bounds__(64) void attn_kernel()
{
    __shared__ float4 Ks[S_LEN];
    __shared__ float4 Vs[S_LEN];
    int bh = blockIdx.x;
    int b = bh >> 1, h = bh & 1;
    int tid = threadIdx.x;
    const float* Kbase = g_K + (size_t)b * S_LEN * 8 + h * 4;
    const float* Vbase = g_V + (size_t)b * S_LEN * 8 + h * 4;
    for (int k = tid; k < S_LEN; k += 64) {
        Ks[k] = *(const float4*)(Kbase + k * 8);
        Vs[k] = *(const float4*)(Vbase + k * 8);
    }
    __syncthreads();
    int q = blockIdx.y * 64 + tid;
    const float* Qp = g_Q + ((size_t)b * S_LEN + q) * 8 + h * 4;
    float qx = Qp[0], qy = Qp[1], qz = Qp[2], qw = Qp[3];
    float den = 0.f;
    float ax = 0.f, ay = 0.f, az = 0.f, aw = 0.f;
    for (int k = 0; k < S_LEN; ++k) {
        float4 kk = Ks[k];
        float s = 0.5f * (qx * kk.x + qy * kk.y + qz * kk.z + qw * kk.w);
        float e = __expf(s);
        den += e;
        float4 vv = Vs[k];
        ax += e * vv.x; ay += e * vv.y; az += e * vv.z; aw += e * vv.w;
    }
    float inv = 1.f / den;
    float* cp = g_C + ((size_t)b * S_LEN + q) * 8 + h * 4;
    cp[0] = ax * inv; cp[1] = ay * inv; cp[2] = az * inv; cp[3] = aw * inv;
}

extern "C" void kernel_launch(void* const* d_in, const int* in_sizes, int n_in,
                              void* d_out, int out_size, void* d_ws, size_t ws_size,
                              hipStream_t stream)
{
    const float* x  = (const float*)d_in[0];
    const float* wq = (const float*)d_in[1];
    const float* wk = (const float*)d_in[2];
    const float* wv = (const float*)d_in[3];
    const float* wc = (const float*)d_in[4];

    qkv_kernel<<<TT / 4, 256, 0, stream>>>(x, wq, wk, wv);
    attn_kernel<<<dim3(B_SZ * H_N, S_LEN / 64), 64, 0, stream>>>();
    outc_kernel<<<TT / 4, 256, 0, stream>>>(wc, (float*)d_out);
}

// Round 9
// 153.534 us; speedup vs baseline: 2.4166x; 2.4166x over previous
//
#include <hip/hip_runtime.h>

#define TT 32768   // B*S tokens
#define S_LEN 1024
#define TB 4       // tokens per wave

// f32 intermediates; fully overwritten each call -> deterministic.
__device__ __align__(16) float g_Q[TT * 8];
__device__ __align__(16) float g_K[TT * 8];
__device__ __align__(16) float g_V[TT * 8];
__device__ __align__(16) float g_C[TT * 8];

// ---------------------------------------------------------------------------
// Exact 8-qubit sim with algebraic ring-folding.
//   circuit = RX(x) embed; [RX(w0), ring] ; [RX(w1), ring] ; <Z_i>
//   = build product state RX(x+w0)|0> at ring-permuted indices,
//     apply RX(w1) butterflies, measure with ring-composed sign masks.
// Index n in [0,256): qubit q <-> bit (7-q); n = lane*4 + j:
//   u_0..u_5 = lane bits 5..0, u_6 = j bit1, u_7 = j bit0.
// Ring as GF(2) map: u_0 = v_1^..^v_7 ; u_k = v_0^..^v_k (k>=1).
//   (verified: classical trace of |10000000> -> |01111111>.)
// Inverse (for build): v_0=u_0^u_7, v_1=u_0^u_1^u_7, v_k=u_{k-1}^u_k (k>=2).
// Measurement (ring2 folded): ev_i = sum_n p(n) * (-1)^(parity(n in A_i)),
//   A_0={q1..q7}, A_i={q0..qi}:
//   lane masks {0x1F,0x30,0x38,0x3C,0x3E,0x3F,0x3F,0x3F}, j masks {3,0,0,0,0,0,2,3}.
// ---------------------------------------------------------------------------

// One batch of TB tokens: angles cx/sx = cos/sin(x/2) per token,
// weights w (16 floats). Writes 8 floats per token to out.
__device__ __forceinline__ void run_circuit_wave(
    const float cx[TB][8], const float sx[TB][8],
    const float* __restrict__ w, int lane, int tok0, float* __restrict__ out)
{
    // uniform weight sincos
    float c0[8], s0[8], c1[8], s1[8];
#pragma unroll
    for (int q = 0; q < 8; ++q) {
        __sincosf(0.5f * w[q],     &s0[q], &c0[q]);
        __sincosf(0.5f * w[8 + q], &s1[q], &c1[q]);
    }

    float re[TB][4], im[TB][4];

    // lane-derived bits
    const int u0 = (lane >> 5) & 1, u1 = (lane >> 4) & 1, u2 = (lane >> 3) & 1;
    const int u3 = (lane >> 2) & 1, u4 = (lane >> 1) & 1, u5 = lane & 1;
    const int v2 = u1 ^ u2, v3 = u2 ^ u3, v4 = u3 ^ u4, v5 = u4 ^ u5;

    // ---- build product state at ring1-permuted indices ----
#pragma unroll
    for (int t = 0; t < TB; ++t) {
        float cq[8], sq[8];
#pragma unroll
        for (int q = 0; q < 8; ++q) {   // cos/sin((x+w0)/2) by angle addition
            cq[q] = cx[t][q] * c0[q] - sx[t][q] * s0[q];
            sq[q] = sx[t][q] * c0[q] + cx[t][q] * s0[q];
        }
#pragma unroll
        for (int j = 0; j < 4; ++j) {
            const int u6 = (j >> 1) & 1, u7 = j & 1;
            const int v0 = u0 ^ u7, v1 = u0 ^ u1 ^ u7, v6 = u5 ^ u6, v7 = u6 ^ u7;
            float f0 = v0 ? sq[0] : cq[0];
            float f1 = v1 ? sq[1] : cq[1];
            float f2 = v2 ? sq[2] : cq[2];
            float f3 = v3 ? sq[3] : cq[3];
            float f4 = v4 ? sq[4] : cq[4];
            float f5 = v5 ? sq[5] : cq[5];
            float f6 = v6 ? sq[6] : cq[6];
            float f7 = v7 ? sq[7] : cq[7];
            float m = ((f0 * f1) * (f2 * f3)) * ((f4 * f5) * (f6 * f7));
            int K = v0 + v1 + v2 + v3 + v4 + v5 + v6 + v7;
            int k1 = K & 1, k2 = K & 2;
            // amp = m * (-i)^K
            re[t][j] = k1 ? 0.f : (k2 ? -m : m);
            im[t][j] = k1 ? (k2 ? m : -m) : 0.f;
        }
    }

    // ---- RX(w1) butterflies ----
#pragma unroll
    for (int q = 0; q < 6; ++q) {       // cross-lane qubits
        const int mask = 1 << (5 - q);
        const float c = c1[q], s = s1[q];
#pragma unroll
        for (int t = 0; t < TB; ++t) {
#pragma unroll
            for (int j = 0; j < 4; ++j) {
                float pr = __shfl_xor(re[t][j], mask);
                float pi = __shfl_xor(im[t][j], mask);
                re[t][j] = c * re[t][j] + s * pi;
                im[t][j] = c * im[t][j] - s * pr;
            }
        }
    }
    {   // qubit 6: slot pairs (0,2),(1,3)
        const float c = c1[6], s = s1[6];
#pragma unroll
        for (int t = 0; t < TB; ++t) {
            float nr0 = c * re[t][0] + s * im[t][2], ni0 = c * im[t][0] - s * re[t][2];
            float nr1 = c * re[t][1] + s * im[t][3], ni1 = c * im[t][1] - s * re[t][3];
            float nr2 = c * re[t][2] + s * im[t][0], ni2 = c * im[t][2] - s * re[t][0];
            float nr3 = c * re[t][3] + s * im[t][1], ni3 = c * im[t][3] - s * re[t][1];
            re[t][0] = nr0; re[t][1] = nr1; re[t][2] = nr2; re[t][3] = nr3;
            im[t][0] = ni0; im[t][1] = ni1; im[t][2] = ni2; im[t][3] = ni3;
        }
    }
    {   // qubit 7: slot pairs (0,1),(2,3)
        const float c = c1[7], s = s1[7];
#pragma unroll
        for (int t = 0; t < TB; ++t) {
            float nr0 = c * re[t][0] + s * im[t][1], ni0 = c * im[t][0] - s * re[t][1];
            float nr1 = c * re[t][1] + s * im[t][0], ni1 = c * im[t][1] - s * re[t][0];
            float nr2 = c * re[t][2] + s * im[t][3], ni2 = c * im[t][2] - s * re[t][3];
            float nr3 = c * re[t][3] + s * im[t][2], ni3 = c * im[t][3] - s * re[t][2];
            re[t][0] = nr0; re[t][1] = nr1; re[t][2] = nr2; re[t][3] = nr3;
            im[t][0] = ni0; im[t][1] = ni1; im[t][2] = ni2; im[t][3] = ni3;
        }
    }

    // ---- measure: probs, j-folds, lane signs, transposed reduce ----
    const float sg1F = (__popc(lane & 0x1F) & 1) ? -1.f : 1.f;
    const float sg30 = (__popc(lane & 0x30) & 1) ? -1.f : 1.f;
    const float sg38 = (__popc(lane & 0x38) & 1) ? -1.f : 1.f;
    const float sg3C = (__popc(lane & 0x3C) & 1) ? -1.f : 1.f;
    const float sg3E = (__popc(lane & 0x3E) & 1) ? -1.f : 1.f;
    const float sg3F = (__popc(lane & 0x3F) & 1) ? -1.f : 1.f;
    const int b0 = lane & 1, b1 = lane & 2, b2 = lane & 4;

#pragma unroll
    for (int t = 0; t < TB; ++t) {
        float p0 = re[t][0] * re[t][0] + im[t][0] * im[t][0];
        float p1 = re[t][1] * re[t][1] + im[t][1] * im[t][1];
        float p2 = re[t][2] * re[t][2] + im[t][2] * im[t][2];
        float p3 = re[t][3] * re[t][3] + im[t][3] * im[t][3];
        float t0 = (p0 + p1) + (p2 + p3);
        float t2 = (p0 + p1) - (p2 + p3);     // sign by u6
        float t3 = (p0 - p1) - (p2 - p3);     // sign by u6^u7
        float a0 = t3 * sg1F;
        float a1 = t0 * sg30;
        float a2 = t0 * sg38;
        float a3 = t0 * sg3C;
        float a4 = t0 * sg3E;
        float a5 = t0 * sg3F;
        float a6 = t2 * sg3F;
        float a7 = t3 * sg3F;
        // butterfly over lane bits 0..2: each lane sums its octet for all 8
#pragma unroll
        for (int mm = 1; mm < 8; mm <<= 1) {
            a0 += __shfl_xor(a0, mm); a1 += __shfl_xor(a1, mm);
            a2 += __shfl_xor(a2, mm); a3 += __shfl_xor(a3, mm);
            a4 += __shfl_xor(a4, mm); a5 += __shfl_xor(a5, mm);
            a6 += __shfl_xor(a6, mm); a7 += __shfl_xor(a7, mm);
        }
        // lane L picks value (L&7), then sum across octets
        float x01 = b0 ? a1 : a0, x23 = b0 ? a3 : a2;
        float x45 = b0 ? a5 : a4, x67 = b0 ? a7 : a6;
        float y0 = b1 ? x23 : x01, y1 = b1 ? x67 : x45;
        float v = b2 ? y1 : y0;
        v += __shfl_xor(v, 8); v += __shfl_xor(v, 16); v += __shfl_xor(v, 32);
        if (lane < 8) out[(tok0 + t) * 8 + lane] = v;
    }
}

__global__ __launch_bounds__(256) void qkv_kernel(
    const float* __restrict__ x, const float* __restrict__ wq,
    const float* __restrict__ wk, const float* __restrict__ wv)
{
    int wvid = (blockIdx.x * 256 + threadIdx.x) >> 6;
    int lane = threadIdx.x & 63;
    int tok0 = wvid * TB;
    float cx[TB][8], sx[TB][8];
#pragma unroll
    for (int t = 0; t < TB; ++t)
#pragma unroll
        for (int q = 0; q < 8; ++q)
            __sincosf(0.5f * x[(tok0 + t) * 8 + q], &sx[t][q], &cx[t][q]);

    run_circuit_wave(cx, sx, wq, lane, tok0, g_Q);
    run_circuit_wave(cx, sx, wk, lane, tok0, g_K);
    run_circuit_wave(cx, sx, wv, lane, tok0, g_V);
}

__global__ __launch_bounds__(256) void outc_kernel(
    const float* __restrict__ wc, float* __restrict__ out)
{
    int wvid = (blockIdx.x * 256 + threadIdx.x) >> 6;
    int lane = threadIdx.x & 63;
    int tok0 = wvid * TB;
    float cx[TB][8], sx[TB][8];
#pragma unroll
    for (int t = 0; t < TB; ++t)
#pragma unroll
        for (int q = 0; q < 8; ++q)
            __sincosf(0.5f * g_C[(tok0 + t) * 8 + q], &sx[t][q], &cx[t][q]);

    run_circuit_wave(cx, sx, wc, lane, tok0, out);
}

// ---------------------------------------------------------------------------
// attention: grid (B*H, S/256), block 256. K,V for one (b,h) in LDS (32 KB).
// |score| <= 2 -> single-pass softmax.
// ---------------------------------------------------------------------------
__global__ __launch_bounds__(256) void attn_kernel()
{
    __shared__ float4 Ks[S_LEN];
    __shared__ float4 Vs[S_LEN];
    int bh = blockIdx.x;
    int b = bh >> 1, h = bh & 1;
    int tid = threadIdx.x;
    const float* Kbase = g_K + (size_t)b * S_LEN * 8 + h * 4;
    const float* Vbase = g_V + (size_t)b * S_LEN * 8 + h * 4;
    for (int k = tid; k < S_LEN; k += 256) {
        Ks[k] = *(const float4*)(Kbase + k * 8);
        Vs[k] = *(const float4*)(Vbase + k * 8);
    }
    __syncthreads();
    int q = blockIdx.y * 256 + tid;
    const float* Qp = g_Q + ((size_t)b * S_LEN + q) * 8 + h * 4;
    float qx = Qp[0], qy = Qp[1], qz = Qp[2], qw = Qp[3];
    float den = 0.f;
    float ax = 0.f, ay = 0.f, az = 0.f, aw = 0.f;
    for (int k = 0; k < S_LEN; ++k) {
        float4 kk = Ks[k];
        float s = 0.5f * (qx * kk.x + qy * kk.y + qz * kk.z + qw * kk.w);
        float e = __expf(s);
        den += e;
        float4 vv = Vs[k];
        ax += e * vv.x; ay += e * vv.y; az += e * vv.z; aw += e * vv.w;
    }
    float inv = 1.f / den;
    float* cp = g_C + ((size_t)b * S_LEN + q) * 8 + h * 4;
    cp[0] = ax * inv; cp[1] = ay * inv; cp[2] = az * inv; cp[3] = aw * inv;
}

extern "C" void kernel_launch(void* const* d_in, const int* in_sizes, int n_in,
                              void* d_out, int out_size, void* d_ws, size_t ws_size,
                              hipStream_t stream)
{
    const float* x  = (const float*)d_in[0];
    const float* wq = (const float*)d_in[1];
    const float* wk = (const float*)d_in[2];
    const float* wv = (const float*)d_in[3];
    const float* wc = (const float*)d_in[4];

    qkv_kernel<<<TT / (TB * 4), 256, 0, stream>>>(x, wq, wk, wv);
    attn_kernel<<<dim3(64, S_LEN / 256), 256, 0, stream>>>();
    outc_kernel<<<TT / (TB * 4), 256, 0, stream>>>(wc, (float*)d_out);
}

// Round 10
// 121.255 us; speedup vs baseline: 3.0599x; 1.2662x over previous
//
#include <hip/hip_runtime.h>

#define TT 32768   // B*S tokens
#define S_LEN 1024
#define TB 8       // tokens per wave

// f32 intermediates; fully overwritten each call -> deterministic.
__device__ __align__(16) float g_Q[TT * 8];
__device__ __align__(16) float g_K[TT * 8];
__device__ __align__(16) float g_V[TT * 8];
__device__ __align__(16) float g_C[TT * 8];
// attention k-split partials (4 chunks x 64 bh x 1024 q)
__device__ __align__(16) float4 gp_acc[4 * 64 * 1024];
__device__ float gp_den[4 * 64 * 1024];

// ---------------------------------------------------------------------------
// Cross-lane XOR helpers. Masks 1,2,8 via DPP (VALU pipe); 4,16,32 via DS.
//   xor1 = quad_perm(1,0,3,2)=0xB1; xor2 = quad_perm(2,3,0,1)=0x4E;
//   xor8 = row_ror:8 = 0x128 ((i+8)&15 == i^8).
// ---------------------------------------------------------------------------
template <int CTRL>
__device__ __forceinline__ float dppx(float v)
{
    return __int_as_float(__builtin_amdgcn_mov_dpp(__float_as_int(v), CTRL, 0xF, 0xF, false));
}
__device__ __forceinline__ float lx1(float v)  { return dppx<0xB1>(v); }
__device__ __forceinline__ float lx2(float v)  { return dppx<0x4E>(v); }
__device__ __forceinline__ float lx8(float v)  { return dppx<0x128>(v); }
__device__ __forceinline__ float lx4(float v)  { return __shfl_xor(v, 4); }
__device__ __forceinline__ float lx16(float v) { return __shfl_xor(v, 16); }
__device__ __forceinline__ float lx32(float v) { return __shfl_xor(v, 32); }

// ---------------------------------------------------------------------------
// Exact 8-qubit sim with ring-folding (algebra identical to the round-9
// passing kernel; only the shuffle mechanics and reduction changed).
// State: product state RX(x+w0)|0> built at ring1-permuted indices,
// RX(w1) butterflies, measurement with ring2-composed parity masks.
// n = lane*4 + j; u0..u5 = lane bits 5..0, u6 = j bit1, u7 = j bit0.
// v (build coords): v0=u0^u7, v1=u0^u1^u7, vk=u_{k-1}^u_k (k>=2).
// Outputs: payload/mask pairs (t3,0x1F),(t0,0x30),(t0,0x38),(t0,0x3C),
// (t0,0x3E),(t0,0x3F),(t2,0x3F),(t3,0x3F) for ev[0..7].
// ---------------------------------------------------------------------------

#define WHT6(v)                                          \
    {                                                    \
        float p;                                         \
        p = lx1(v);  v = (lane & 1)  ? p - v : v + p;    \
        p = lx2(v);  v = (lane & 2)  ? p - v : v + p;    \
        p = lx4(v);  v = (lane & 4)  ? p - v : v + p;    \
        p = lx8(v);  v = (lane & 8)  ? p - v : v + p;    \
        p = lx16(v); v = (lane & 16) ? p - v : v + p;    \
        p = lx32(v); v = (lane & 32) ? p - v : v + p;    \
    }

__device__ __forceinline__ void run_circuit_wave(
    const float* __restrict__ xbase, const float* __restrict__ w,
    int lane, int tok0, float* __restrict__ out)
{
    // layer-2 weight sincos (uniform)
    float c1[8], s1[8];
#pragma unroll
    for (int q = 0; q < 8; ++q)
        __sincosf(0.5f * w[8 + q], &s1[q], &c1[q]);

    // lane-derived bits
    const int u0 = (lane >> 5) & 1, u1 = (lane >> 4) & 1, u2 = (lane >> 3) & 1;
    const int u3 = (lane >> 2) & 1, u4 = (lane >> 1) & 1, u5 = lane & 1;
    const int v2 = u1 ^ u2, v3 = u2 ^ u3, v4 = u3 ^ u4, v5 = u4 ^ u5;
    const int K2345 = v2 + v3 + v4 + v5;

    float re[TB][4], im[TB][4];

    // ---- build product state at ring1-permuted indices ----
#pragma unroll
    for (int t = 0; t < TB; ++t) {
        const float* xt = xbase + (tok0 + t) * 8;
        float cq[8], sq[8];
#pragma unroll
        for (int q = 0; q < 8; ++q)
            __sincosf(0.5f * xt[q] + 0.5f * w[q], &sq[q], &cq[q]);
        float f2345 = (v2 ? sq[2] : cq[2]) * (v3 ? sq[3] : cq[3]) *
                      (v4 ? sq[4] : cq[4]) * (v5 ? sq[5] : cq[5]);
#pragma unroll
        for (int j = 0; j < 4; ++j) {
            const int u6 = (j >> 1) & 1, u7 = j & 1;
            const int v0 = u0 ^ u7, v1 = u0 ^ u1 ^ u7, v6 = u5 ^ u6, v7 = u6 ^ u7;
            float m = (v0 ? sq[0] : cq[0]) * (v1 ? sq[1] : cq[1]) *
                      (v6 ? sq[6] : cq[6]) * (v7 ? sq[7] : cq[7]) * f2345;
            int K = (K2345 + v0 + v1 + v6 + v7) & 3;
            re[t][j] = (K & 1) ? 0.f : ((K & 2) ? -m : m);
            im[t][j] = (K & 1) ? ((K & 2) ? m : -m) : 0.f;
        }
    }

    // ---- RX(w1) butterflies ----
#define BFLY(LXF, Q)                                            \
    {                                                           \
        const float c = c1[Q], s = s1[Q];                       \
        _Pragma("unroll")                                       \
        for (int t = 0; t < TB; ++t) {                          \
            _Pragma("unroll")                                   \
            for (int j = 0; j < 4; ++j) {                       \
                float pr = LXF(re[t][j]);                       \
                float pi = LXF(im[t][j]);                       \
                re[t][j] = c * re[t][j] + s * pi;               \
                im[t][j] = c * im[t][j] - s * pr;               \
            }                                                   \
        }                                                       \
    }
    BFLY(lx32, 0)
    BFLY(lx16, 1)
    BFLY(lx8, 2)
    BFLY(lx4, 3)
    BFLY(lx2, 4)
    BFLY(lx1, 5)
#undef BFLY
    {   // qubit 6: slot pairs (0,2),(1,3)
        const float c = c1[6], s = s1[6];
#pragma unroll
        for (int t = 0; t < TB; ++t) {
            float nr0 = c * re[t][0] + s * im[t][2], ni0 = c * im[t][0] - s * re[t][2];
            float nr1 = c * re[t][1] + s * im[t][3], ni1 = c * im[t][1] - s * re[t][3];
            float nr2 = c * re[t][2] + s * im[t][0], ni2 = c * im[t][2] - s * re[t][0];
            float nr3 = c * re[t][3] + s * im[t][1], ni3 = c * im[t][3] - s * re[t][1];
            re[t][0] = nr0; re[t][1] = nr1; re[t][2] = nr2; re[t][3] = nr3;
            im[t][0] = ni0; im[t][1] = ni1; im[t][2] = ni2; im[t][3] = ni3;
        }
    }
    {   // qubit 7: slot pairs (0,1),(2,3)
        const float c = c1[7], s = s1[7];
#pragma unroll
        for (int t = 0; t < TB; ++t) {
            float nr0 = c * re[t][0] + s * im[t][1], ni0 = c * im[t][0] - s * re[t][1];
            float nr1 = c * re[t][1] + s * im[t][0], ni1 = c * im[t][1] - s * re[t][0];
            float nr2 = c * re[t][2] + s * im[t][3], ni2 = c * im[t][2] - s * re[t][3];
            float nr3 = c * re[t][3] + s * im[t][2], ni3 = c * im[t][3] - s * re[t][2];
            re[t][0] = nr0; re[t][1] = nr1; re[t][2] = nr2; re[t][3] = nr3;
            im[t][0] = ni0; im[t][1] = ni1; im[t][2] = ni2; im[t][3] = ni3;
        }
    }

    // ---- measurement: j-folds, 3 signed WHTs, bpermute gather, store ----
    const int srctab[8] = {0x1F, 0x30, 0x38, 0x3C, 0x3E, 0x3F, 0x3F, 0x3F};
    const int src4 = srctab[lane & 7] << 2;

#pragma unroll
    for (int t = 0; t < TB; ++t) {
        float p0 = re[t][0] * re[t][0] + im[t][0] * im[t][0];
        float p1 = re[t][1] * re[t][1] + im[t][1] * im[t][1];
        float p2 = re[t][2] * re[t][2] + im[t][2] * im[t][2];
        float p3 = re[t][3] * re[t][3] + im[t][3] * im[t][3];
        float t0 = (p0 + p1) + (p2 + p3);
        float t2 = (p0 + p1) - (p2 + p3);
        float t3 = (p0 - p1) - (p2 - p3);
        WHT6(t0)
        WHT6(t2)
        WHT6(t3)
        float g0 = __int_as_float(__builtin_amdgcn_ds_bpermute(src4, __float_as_int(t0)));
        float g2 = __int_as_float(__builtin_amdgcn_ds_bpermute(src4, __float_as_int(t2)));
        float g3 = __int_as_float(__builtin_amdgcn_ds_bpermute(src4, __float_as_int(t3)));
        float val = (lane == 0) ? g3 : ((lane <= 5) ? g0 : ((lane == 6) ? g2 : g3));
        if (lane < 8) out[(tok0 + t) * 8 + lane] = val;
    }
}

__global__ __launch_bounds__(256) void qkv_kernel(
    const float* __restrict__ x, const float* __restrict__ wq,
    const float* __restrict__ wk, const float* __restrict__ wv)
{
    int lane = threadIdx.x & 63;
    int wvid = __builtin_amdgcn_readfirstlane(blockIdx.x * 4 + (threadIdx.x >> 6));
    int tok0 = wvid * TB;
    run_circuit_wave(x, wq, lane, tok0, g_Q);
    run_circuit_wave(x, wk, lane, tok0, g_K);
    run_circuit_wave(x, wv, lane, tok0, g_V);
}

__global__ __launch_bounds__(256) void outc_kernel(
    const float* __restrict__ wc, float* __restrict__ out)
{
    int lane = threadIdx.x & 63;
    int wvid = __builtin_amdgcn_readfirstlane(blockIdx.x * 4 + (threadIdx.x >> 6));
    int tok0 = wvid * TB;
    run_circuit_wave(g_C, wc, lane, tok0, out);
}

// ---------------------------------------------------------------------------
// attention, k-split x4: partial (num,den) per 256-k chunk, then merge.
// |score| <= 2 -> single-pass softmax (no max subtraction).
// ---------------------------------------------------------------------------
__global__ __launch_bounds__(256) void attn_part()
{
    __shared__ float4 Ks[256];
    __shared__ float4 Vs[256];
    int bh = blockIdx.x, qc = blockIdx.y, kc = blockIdx.z;
    int b = bh >> 1, h = bh & 1;
    int tid = threadIdx.x;
    const float* KVrow = g_K + ((size_t)b * S_LEN + kc * 256 + tid) * 8 + h * 4;
    Ks[tid] = *(const float4*)KVrow;
    Vs[tid] = *(const float4*)(KVrow + (g_V - g_K));
    __syncthreads();
    int q = qc * 256 + tid;
    const float* Qp = g_Q + ((size_t)b * S_LEN + q) * 8 + h * 4;
    float4 qv = *(const float4*)Qp;
    float den = 0.f;
    float4 acc = make_float4(0.f, 0.f, 0.f, 0.f);
    for (int k = 0; k < 256; ++k) {
        float4 kk = Ks[k];
        float s = 0.5f * (qv.x * kk.x + qv.y * kk.y + qv.z * kk.z + qv.w * kk.w);
        float e = __expf(s);
        den += e;
        float4 vv = Vs[k];
        acc.x += e * vv.x; acc.y += e * vv.y; acc.z += e * vv.z; acc.w += e * vv.w;
    }
    int idx = kc * 65536 + bh * 1024 + q;
    gp_acc[idx] = acc;
    gp_den[idx] = den;
}

__global__ __launch_bounds__(256) void attn_merge()
{
    int idx = blockIdx.x * 256 + threadIdx.x;    // bh*1024 + q
    float4 A = make_float4(0.f, 0.f, 0.f, 0.f);
    float D = 0.f;
#pragma unroll
    for (int kc = 0; kc < 4; ++kc) {
        float4 a = gp_acc[kc * 65536 + idx];
        A.x += a.x; A.y += a.y; A.z += a.z; A.w += a.w;
        D += gp_den[kc * 65536 + idx];
    }
    float inv = 1.f / D;
    int bh = idx >> 10, q = idx & 1023;
    int b = bh >> 1, h = bh & 1;
    float* cp = g_C + ((size_t)b * S_LEN + q) * 8 + h * 4;
    cp[0] = A.x * inv; cp[1] = A.y * inv; cp[2] = A.z * inv; cp[3] = A.w * inv;
}

extern "C" void kernel_launch(void* const* d_in, const int* in_sizes, int n_in,
                              void* d_out, int out_size, void* d_ws, size_t ws_size,
                              hipStream_t stream)
{
    const float* x  = (const float*)d_in[0];
    const float* wq = (const float*)d_in[1];
    const float* wk = (const float*)d_in[2];
    const float* wv = (const float*)d_in[3];
    const float* wc = (const float*)d_in[4];

    qkv_kernel<<<TT / (TB * 4), 256, 0, stream>>>(x, wq, wk, wv);
    attn_part<<<dim3(64, 4, 4), 256, 0, stream>>>();
    attn_merge<<<256, 256, 0, stream>>>();
    outc_kernel<<<TT / (TB * 4), 256, 0, stream>>>(wc, (float*)d_out);
}

// Round 11
// 46.336 us; speedup vs baseline: 8.0072x; 2.6169x over previous
//
#include <hip/hip_runtime.h>

#define TT 32768   // B*S tokens
#define S_LEN 1024

// intermediates; fully overwritten each call -> deterministic.
__device__ __align__(16) float g_Q[TT * 8];
__device__ __align__(16) float g_K[TT * 8];
__device__ __align__(16) float g_V[TT * 8];
__device__ __align__(16) float4 gp_acc[4 * 64 * 1024];
__device__ float gp_den[4 * 64 * 1024];
__device__ float g_coef[4][8][128];   // per-circuit uniform term coefficients

// ---------------------------------------------------------------------------
// Compile-time Pauli-backpropagation term tables.
// Circuit: |0> -RX(x)-RX(w0)- ring - RX(w1) - ring - measure Z_i,
// folded as ev_i = <psi| R1' L2' R2' Z_i R2 L2 R1 |psi>,
// psi = prod_q RX(theta_q)|0>, theta_q = x_q + w0_q.
// CNOT(c,t) conjugation on Pauli bitmasks is sign-free:
//   Z-pattern: a_t=1 -> toggle a_c ; X-pattern: b_c=1 -> toggle b_t.
// Ring applied to state as CNOT(0,1)..CNOT(7,0); observable conjugation
// therefore applies q=7 down to q=0.
// RX(w1)' Z RX(w1) = cos(w1) Z + sin(w1) * i * XZ  (full angle).
// Per-qubit expectations: <I>=1, <Z>=cos th, <XZ>=i sin th, <X>=0.
// Survival: X-support subset of Z-support; phase i^(|T|+|b3|) must be +-1.
// The constexpr-derived A'_i supports reproduce the mask tables of the
// hardware-validated round-9/10 statevector kernels (checked ev0, ev1, ...).
// ---------------------------------------------------------------------------
struct PTerm { unsigned ymask, zonly, tmask; float sgn; };
struct OTab { PTerm t[128]; int n; unsigned amask; };

constexpr unsigned conjZring(unsigned a) {
    for (int q = 7; q >= 0; --q) {
        const int c = q, tt = (q + 1) & 7;
        if ((a >> tt) & 1u) a ^= (1u << c);
    }
    return a;
}
constexpr unsigned conjXring(unsigned b) {
    for (int q = 7; q >= 0; --q) {
        const int c = q, tt = (q + 1) & 7;
        if ((b >> c) & 1u) b ^= (1u << tt);
    }
    return b;
}
constexpr int popc8(unsigned v) { int n = 0; for (int i = 0; i < 8; ++i) n += (v >> i) & 1; return n; }

constexpr OTab build_tab(int i) {
    OTab o{};
    o.n = 0;
    const unsigned a1 = conjZring(1u << i);   // Z-support after ring2 conj
    o.amask = a1;
    const unsigned a3 = conjZring(a1);        // Z-support after ring1 conj
    unsigned T = a1;
    while (true) {
        const unsigned b3 = conjXring(T);     // X-support after ring1 conj
        if (!(b3 & ~a3)) {                    // survives (no bare X)
            const int k = popc8(T) + popc8(b3);
            const int idx = (k & 1) ? 100000 : o.n;   // odd phase => compile error
            o.t[idx].ymask = b3;
            o.t[idx].zonly = a3 & ~b3;
            o.t[idx].tmask = T;
            o.t[idx].sgn = ((k >> 1) & 1) ? -1.f : 1.f;   // i^k, k even
            o.n++;
        }
        if (T == 0) break;
        T = (T - 1) & a1;
    }
    return o;
}

constexpr OTab g_tab[8] = {build_tab(0), build_tab(1), build_tab(2), build_tab(3),
                           build_tab(4), build_tab(5), build_tab(6), build_tab(7)};
static_assert(g_tab[0].n >= 1 && g_tab[0].n <= 128, "term count");
static_assert(g_tab[7].n >= 1 && g_tab[7].n <= 128, "term count");

// ---- prologue: per-circuit uniform coefficients  prod sin/cos(w1) ----
template <int I>
__device__ __forceinline__ void coef_one(const float s1[8], const float c1[8], float* dst)
{
    constexpr OTab tb = g_tab[I];
#pragma unroll
    for (int k = 0; k < tb.n; ++k) {
        float c = tb.t[k].sgn;
#pragma unroll
        for (int q = 0; q < 8; ++q) {
            if ((tb.t[k].tmask >> q) & 1) c *= s1[q];
            else if ((tb.amask >> q) & 1) c *= c1[q];
        }
        dst[k] = c;
    }
}

__global__ __launch_bounds__(64) void precoef(
    const float* __restrict__ wq, const float* __restrict__ wk,
    const float* __restrict__ wv, const float* __restrict__ wc)
{
    int tid = threadIdx.x;
    if (tid >= 32) return;
    int set = tid >> 3, i = tid & 7;
    const float* w = (set == 0) ? wq : (set == 1) ? wk : (set == 2) ? wv : wc;
    float s1[8], c1[8];
#pragma unroll
    for (int q = 0; q < 8; ++q) __sincosf(w[8 + q], &s1[q], &c1[q]);   // full angle
    float* dst = &g_coef[set][i][0];
    switch (i) {
        case 0: coef_one<0>(s1, c1, dst); break;
        case 1: coef_one<1>(s1, c1, dst); break;
        case 2: coef_one<2>(s1, c1, dst); break;
        case 3: coef_one<3>(s1, c1, dst); break;
        case 4: coef_one<4>(s1, c1, dst); break;
        case 5: coef_one<5>(s1, c1, dst); break;
        case 6: coef_one<6>(s1, c1, dst); break;
        case 7: coef_one<7>(s1, c1, dst); break;
    }
}

// ---- per-token evaluation: ev_i = sum_k coef * prod sin(th)/cos(th) ----
template <int I>
__device__ __forceinline__ float eval_out(const float cs[8], const float sn[8],
                                          const float* __restrict__ coefI)
{
    constexpr OTab tb = g_tab[I];
    float acc = 0.f;
#pragma unroll
    for (int k = 0; k < tb.n; ++k) {
        float p = coefI[k];
#pragma unroll
        for (int q = 0; q < 8; ++q) {
            if ((tb.t[k].ymask >> q) & 1) p *= sn[q];
            else if ((tb.t[k].zonly >> q) & 1) p *= cs[q];
        }
        acc += p;
    }
    return acc;
}

__device__ __forceinline__ void eval_all(const float th[8],
                                         const float (*__restrict__ coef)[128],
                                         float ev[8])
{
    float cs[8], sn[8];
#pragma unroll
    for (int q = 0; q < 8; ++q) __sincosf(th[q], &sn[q], &cs[q]);   // full angle
    ev[0] = eval_out<0>(cs, sn, coef[0]);
    ev[1] = eval_out<1>(cs, sn, coef[1]);
    ev[2] = eval_out<2>(cs, sn, coef[2]);
    ev[3] = eval_out<3>(cs, sn, coef[3]);
    ev[4] = eval_out<4>(cs, sn, coef[4]);
    ev[5] = eval_out<5>(cs, sn, coef[5]);
    ev[6] = eval_out<6>(cs, sn, coef[6]);
    ev[7] = eval_out<7>(cs, sn, coef[7]);
}

// ---- Q/K/V: one token per lane, circuit selected by blockIdx.y ----
__global__ __launch_bounds__(256) void qkv_pauli(
    const float* __restrict__ x, const float* __restrict__ wq,
    const float* __restrict__ wk, const float* __restrict__ wv)
{
    int t = blockIdx.x * 256 + threadIdx.x;
    int set = blockIdx.y;
    const float* w = (set == 0) ? wq : (set == 1) ? wk : wv;
    float* out = (set == 0) ? g_Q : (set == 1) ? g_K : g_V;
    float4 xa = ((const float4*)x)[t * 2];
    float4 xb = ((const float4*)x)[t * 2 + 1];
    float th[8] = {xa.x + w[0], xa.y + w[1], xa.z + w[2], xa.w + w[3],
                   xb.x + w[4], xb.y + w[5], xb.z + w[6], xb.w + w[7]};
    float ev[8];
    eval_all(th, g_coef[set], ev);
    ((float4*)out)[t * 2]     = make_float4(ev[0], ev[1], ev[2], ev[3]);
    ((float4*)out)[t * 2 + 1] = make_float4(ev[4], ev[5], ev[6], ev[7]);
}

// ---- attention, k-split x4 (structure identical to the passing round-10) ----
__global__ __launch_bounds__(256) void attn_part()
{
    __shared__ float4 Ks[256];
    __shared__ float4 Vs[256];
    int bh = blockIdx.x, qc = blockIdx.y, kc = blockIdx.z;
    int b = bh >> 1, h = bh & 1;
    int tid = threadIdx.x;
    size_t row = (size_t)b * S_LEN + kc * 256 + tid;
    Ks[tid] = *(const float4*)(g_K + row * 8 + h * 4);
    Vs[tid] = *(const float4*)(g_V + row * 8 + h * 4);
    __syncthreads();
    int q = qc * 256 + tid;
    const float* Qp = g_Q + ((size_t)b * S_LEN + q) * 8 + h * 4;
    float4 qv = *(const float4*)Qp;
    float den = 0.f;
    float4 acc = make_float4(0.f, 0.f, 0.f, 0.f);
    for (int k = 0; k < 256; ++k) {
        float4 kk = Ks[k];
        float s = 0.5f * (qv.x * kk.x + qv.y * kk.y + qv.z * kk.z + qv.w * kk.w);
        float e = __expf(s);                     // |s| <= 2, no max pass needed
        den += e;
        float4 vv = Vs[k];
        acc.x += e * vv.x; acc.y += e * vv.y; acc.z += e * vv.z; acc.w += e * vv.w;
    }
    int idx = kc * 65536 + bh * 1024 + q;
    gp_acc[idx] = acc;
    gp_den[idx] = den;
}

// ---- output circuit with fused k-split merge ----
__global__ __launch_bounds__(256) void outc_pauli(
    const float* __restrict__ wc, float* __restrict__ out)
{
    int t = blockIdx.x * 256 + threadIdx.x;
    int b = t >> 10, s = t & 1023;
    float th[8];
#pragma unroll
    for (int h = 0; h < 2; ++h) {
        float4 A = make_float4(0.f, 0.f, 0.f, 0.f);
        float D = 0.f;
#pragma unroll
        for (int kc = 0; kc < 4; ++kc) {
            int idx = kc * 65536 + (b * 2 + h) * 1024 + s;
            float4 a = gp_acc[idx];
            A.x += a.x; A.y += a.y; A.z += a.z; A.w += a.w;
            D += gp_den[idx];
        }
        float inv = 1.f / D;
        th[h * 4 + 0] = A.x * inv + wc[h * 4 + 0];
        th[h * 4 + 1] = A.y * inv + wc[h * 4 + 1];
        th[h * 4 + 2] = A.z * inv + wc[h * 4 + 2];
        th[h * 4 + 3] = A.w * inv + wc[h * 4 + 3];
    }
    float ev[8];
    eval_all(th, g_coef[3], ev);
    ((float4*)out)[t * 2]     = make_float4(ev[0], ev[1], ev[2], ev[3]);
    ((float4*)out)[t * 2 + 1] = make_float4(ev[4], ev[5], ev[6], ev[7]);
}

extern "C" void kernel_launch(void* const* d_in, const int* in_sizes, int n_in,
                              void* d_out, int out_size, void* d_ws, size_t ws_size,
                              hipStream_t stream)
{
    const float* x  = (const float*)d_in[0];
    const float* wq = (const float*)d_in[1];
    const float* wk = (const float*)d_in[2];
    const float* wv = (const float*)d_in[3];
    const float* wc = (const float*)d_in[4];

    precoef<<<1, 64, 0, stream>>>(wq, wk, wv, wc);
    qkv_pauli<<<dim3(TT / 256, 3), 256, 0, stream>>>(x, wq, wk, wv);
    attn_part<<<dim3(64, 4, 4), 256, 0, stream>>>();
    outc_pauli<<<TT / 256, 256, 0, stream>>>(wc, (float*)d_out);
}